// Round 8
// baseline (4757.460 us; speedup 1.0000x reference)
//
#include <hip/hip_runtime.h>
#include <cstdint>

#define NS 2048      // states S
#define NE 65536     // arcs E
#define ND 2048      // pdfs D
#define NB 32        // batch
#define NT 500       // frames
#define NGROUPS 32   // 64-state dest groups
#define ELLCAP (2*NE)   // uint4 entries; padded total ~102K < 131072
#define LEAKYF 0.1f
#define NBG 16       // batch groups (2 batches each)
#define NSP 16       // state partitions (128 states each)

// ws byte offsets
#define WS_COUNTS 0
#define WS_CURSOR 8192
#define WS_WIDTHS 16384
#define WS_GBASE  16640
#define WS_FLAGS  16896      // 16 bg x 16 producers x 4B = 1 KB
#define WS_ALBUF  20480      // 2 par x 16 bg x 2048 x 8B = 512 KB
#define WS_ARC    544768     // ELLCAP * 16B = 2 MB

// ---- per-op device-coherent (L3) access, NO cache-wide fences ----
__device__ __forceinline__ void st_pair2(float2* p, float2 v) {
    union { float f[2]; unsigned long long u; } q; q.f[0] = v.x; q.f[1] = v.y;
    __hip_atomic_store(reinterpret_cast<unsigned long long*>(p), q.u,
                       __ATOMIC_RELAXED, __HIP_MEMORY_SCOPE_AGENT);
}
__device__ __forceinline__ float2 ld_pair2(const float2* p) {
    unsigned long long u = __hip_atomic_load(
        reinterpret_cast<const unsigned long long*>(p),
        __ATOMIC_RELAXED, __HIP_MEMORY_SCOPE_AGENT);
    union { unsigned long long u; float f[2]; } q; q.u = u;
    return make_float2(q.f[0], q.f[1]);
}
__device__ __forceinline__ void st_flag(uint32_t* p, uint32_t v) {
    __hip_atomic_store(p, v, __ATOMIC_RELAXED, __HIP_MEMORY_SCOPE_AGENT);
}
__device__ __forceinline__ uint32_t ld_flag(const uint32_t* p) {
    return __hip_atomic_load(p, __ATOMIC_RELAXED, __HIP_MEMORY_SCOPE_AGENT);
}

__global__ void k_init(const float* __restrict__ log_init, float* albuf,
                       uint32_t* counts, uint32_t* cursor, uint4* arcp,
                       uint32_t* flags, float* out) {
    int tid = blockIdx.x * blockDim.x + threadIdx.x;
    int n = blockDim.x * gridDim.x;
    for (int i = tid; i < NS; i += n) { counts[i] = 0u; cursor[i] = 0u; }
    for (int i = tid; i < ELLCAP; i += n) arcp[i] = make_uint4(0u, 0u, 0u, 0u);
    for (int i = tid; i < NBG * NS; i += n) {
        int s = i & (NS - 1);
        float a = __expf(log_init[s]);
        reinterpret_cast<float2*>(albuf)[i] = make_float2(a, a);  // parity0: [bg][s]
    }
    for (int i = tid; i < NBG * NSP; i += n) flags[i] = 0u;       // "alpha_0 ready"
    if (tid == 0) out[0] = 0.0f;
}

__global__ void k_count(const int* __restrict__ to_state, uint32_t* counts) {
    int e = blockIdx.x * blockDim.x + threadIdx.x;
    if (e < NE) atomicAdd(&counts[to_state[e]], 1u);
}

__global__ void k_widths(const uint32_t* __restrict__ counts, uint32_t* widths, uint32_t* gbase) {
    int g = threadIdx.x;
    if (g < NGROUPS) {
        uint32_t w = 0u;
        for (int i = 0; i < 64; ++i) w = max(w, counts[g*64 + i]);
        widths[g] = w;
    }
    __syncthreads();
    if (threadIdx.x == 0) {
        uint32_t acc = 0u;
        for (int g2 = 0; g2 < NGROUPS; ++g2) { gbase[g2] = acc; acc += widths[g2] * 64u; }
        gbase[NGROUPS] = acc;
    }
}

__global__ void k_scatter(const int* __restrict__ from_state, const int* __restrict__ to_state,
                          const int* __restrict__ pdf_ids, const float* __restrict__ log_w,
                          const float* __restrict__ log_init,
                          const uint32_t* __restrict__ gbase, uint32_t* cursor, uint4* arcp) {
    int e = blockIdx.x * blockDim.x + threadIdx.x;
    if (e >= NE) return;
    int s = to_state[e];
    int g = s >> 6;
    uint32_t slot = atomicAdd(&cursor[s], 1u);
    uint32_t pos = gbase[g] + slot * 64u + (uint32_t)(s & 63);
    int fs = from_state[e];
    uint32_t meta = (uint32_t)fs | ((uint32_t)pdf_ids[e] << 16);
    float w  = __expf(log_w[e]);
    float w2 = LEAKYF * __expf(log_init[fs]) * w;   // leaky-path weight
    arcp[pos] = make_uint4(meta, __float_as_uint(w), __float_as_uint(w2), 0u);
}

// 256 persistent WGs: bid = sp*16 + bg -> bid%8 = bg%8 (XCD-locked batch groups).
// Per-producer flags: consumer wave w spins ONLY on producer w's flag, then loads
// ONLY that 1KB chunk -> detection + alpha transfer overlap across 16 producers.
// 2 barriers/step. invT folded into arc pass (T known after (B2) from red).
__global__ __launch_bounds__(1024, 1) void k_fwd(
    const float* __restrict__ x, const float* __restrict__ log_final,
    const uint4* __restrict__ arc, const uint32_t* __restrict__ widths,
    const uint32_t* __restrict__ gbase,
    float* __restrict__ albuf, uint32_t* __restrict__ flags, float* out)
{
    __shared__ __align__(16) float2 e2[NS];        // 16 KB raw alpha
    __shared__ __align__(16) float2 Xs[2][ND];     // 32 KB exp(x) double-buffered
    __shared__ __align__(16) float2 pt[16][64];    // 8 KB combined partials
    __shared__ __align__(16) float2 red[16];

    const int tid  = threadIdx.x;
    const int bg   = blockIdx.x & 15;
    const int sp   = blockIdx.x >> 4;
    const int lane = tid & 63;
    const int wid  = tid >> 6;
    const int g    = sp * 2 + (wid >> 3);   // my dest group
    const int wsl  = wid & 7;               // slot-slice (8 waves/group)

    const float* x0 = x + (size_t)(bg * 2)     * NT * ND;
    const float* x1 = x + (size_t)(bg * 2 + 1) * NT * ND;

    // Xs[0] prologue (ordered vs t=0 arc pass by (B2))
    Xs[0][tid]        = make_float2(__expf(x0[tid]),        __expf(x1[tid]));
    Xs[0][tid + 1024] = make_float2(__expf(x0[tid + 1024]), __expf(x1[tid + 1024]));

    const int wd = (int)widths[g];
    const uint4* ap = arc + gbase[g] + lane;     // slot i at ap[i*64]
    uint32_t* myflags = flags + bg * NSP;        // 64B line per batch-group

    float C0 = 0.f, C1 = 0.f;

    for (int t = 0; t < NT; ++t) {
        const int par = t & 1;
        const float2* cbuf = reinterpret_cast<const float2*>(albuf)
                             + ((size_t)par * NBG + bg) * NS;
        float2* nbuf = reinterpret_cast<float2*>(albuf)
                       + ((size_t)(par ^ 1) * NBG + bg) * NS;

        // wave w: spin on producer w's flag (alpha_t chunk w ready)
        while (ld_flag(myflags + wid) < (uint32_t)t)
            __builtin_amdgcn_s_sleep(1);
        __builtin_amdgcn_sched_barrier(0);

        // load producer wid's 128-state chunk (coherent, 1 KB)
        float2 A0 = ld_pair2(cbuf + (wid << 7) + lane);
        float2 A1 = ld_pair2(cbuf + (wid << 7) + 64 + lane);

        // x(t+1) prefetch (issued after chunk loads; drains later with Xs fill)
        float pa0, pa1, pb0, pb1;
        const bool pf = (t + 1 < NT);
        if (pf) {
            const size_t o = (size_t)(t + 1) * ND;
            pa0 = x0[o + tid];        pb0 = x1[o + tid];
            pa1 = x0[o + tid + 1024]; pb1 = x1[o + tid + 1024];
        }

        e2[(wid << 7) + lane]      = A0;
        e2[(wid << 7) + 64 + lane] = A1;
        float u0 = A0.x + A1.x, u1 = A0.y + A1.y;
        #pragma unroll
        for (int off = 32; off > 0; off >>= 1) {
            u0 += __shfl_down(u0, off, 64);
            u1 += __shfl_down(u1, off, 64);
        }
        if (lane == 0) red[wid] = make_float2(u0, u1);
        __syncthreads();   // (B2): e2 + red + Xs[par] ready

        // every wave computes T (16 LDS reads, cheap) -> invT folded into arc pass
        float T0 = 0.f, T1 = 0.f;
        #pragma unroll
        for (int j = 0; j < 16; ++j) { float2 q = red[j]; T0 += q.x; T1 += q.y; }
        const float i0 = 1.0f / T0, i1 = 1.0f / T1;
        if (tid == 0) { C0 += __logf(T0); C1 += __logf(T1); }

        // arc pass: out = sum X[pdf] * (a[src]*invT*w + w2)
        float2 acc = make_float2(0.f, 0.f);
        for (int i = wsl; i < wd; i += 8) {
            uint4 A = ap[(size_t)i * 64];
            const float w  = __uint_as_float(A.y);
            const float w2 = __uint_as_float(A.z);
            const int src = (int)(A.x & 0xFFFFu);
            const int pdf = (int)(A.x >> 16);
            float2 ev = e2[src];
            float2 xv = Xs[par][pdf];
            acc.x = fmaf(xv.x, fmaf(ev.x * i0, w, w2), acc.x);
            acc.y = fmaf(xv.y, fmaf(ev.y * i1, w, w2), acc.y);
        }
        pt[wid][lane] = acc;
        if (pf) {   // exp into the other Xs buffer
            Xs[par ^ 1][tid]        = make_float2(__expf(pa0), __expf(pb0));
            Xs[par ^ 1][tid + 1024] = make_float2(__expf(pa1), __expf(pb1));
        }
        __syncthreads();   // (C): pt ready

        // wave-0 tail: reduce 8+8 wave-partials, store 128 states, drain, flag.
        // Other 15 waves run ahead to the t+1 spin (no trailing barrier).
        if (wid == 0) {
            float2 r0 = pt[0][lane], r1 = pt[8][lane];
            #pragma unroll
            for (int k = 1; k < 8; ++k) {
                float2 qa = pt[k][lane];     r0.x += qa.x; r0.y += qa.y;
                float2 qb = pt[8 + k][lane]; r1.x += qb.x; r1.y += qb.y;
            }
            st_pair2(nbuf + (sp << 7) + lane,      r0);
            st_pair2(nbuf + (sp << 7) + 64 + lane, r1);
            // wave-scope release: drain coherent stores (at L3) -- no cache flush
            asm volatile("s_waitcnt vmcnt(0)" ::: "memory");
            if (lane == 0) st_flag(myflags + sp, (uint32_t)(t + 1));
        }
    }

    // epilogue: sp==0 WG per batch-group; final alpha in parity 0 (NT even)
    if (sp == 0) {
        while (ld_flag(myflags + wid) < (uint32_t)NT)
            __builtin_amdgcn_s_sleep(1);
        __builtin_amdgcn_sched_barrier(0);
        const float2* fbuf = reinterpret_cast<const float2*>(albuf) + (size_t)bg * NS;
        float2 A0 = ld_pair2(fbuf + (wid << 7) + lane);
        float2 A1 = ld_pair2(fbuf + (wid << 7) + 64 + lane);
        float f0 = __expf(log_final[(wid << 7) + lane]);
        float f1 = __expf(log_final[(wid << 7) + 64 + lane]);
        float u0 = A0.x * f0 + A1.x * f1;
        float u1 = A0.y * f0 + A1.y * f1;
        #pragma unroll
        for (int off = 32; off > 0; off >>= 1) {
            u0 += __shfl_down(u0, off, 64);
            u1 += __shfl_down(u1, off, 64);
        }
        if (lane == 0) red[wid] = make_float2(u0, u1);
        __syncthreads();
        if (tid == 0) {
            float t0 = 0.f, t1 = 0.f;
            #pragma unroll
            for (int j = 0; j < 16; ++j) { t0 += red[j].x; t1 += red[j].y; }
            atomicAdd(out, -(__logf(t0) + C0) - (__logf(t1) + C1));
        }
    }
}

extern "C" void kernel_launch(void* const* d_in, const int* in_sizes, int n_in,
                              void* d_out, int out_size, void* d_ws, size_t ws_size,
                              hipStream_t stream) {
    const float* x         = (const float*)d_in[0];
    const float* log_w     = (const float*)d_in[1];
    const float* log_init  = (const float*)d_in[2];
    const float* log_final = (const float*)d_in[3];
    const int*   from_st   = (const int*)d_in[4];
    const int*   to_st     = (const int*)d_in[5];
    const int*   pdf_ids   = (const int*)d_in[6];
    float* out = (float*)d_out;

    uint8_t* ws = (uint8_t*)d_ws;
    uint32_t* counts = (uint32_t*)(ws + WS_COUNTS);
    uint32_t* cursor = (uint32_t*)(ws + WS_CURSOR);
    uint32_t* widths = (uint32_t*)(ws + WS_WIDTHS);
    uint32_t* gbase  = (uint32_t*)(ws + WS_GBASE);
    uint32_t* flags  = (uint32_t*)(ws + WS_FLAGS);
    float*    albuf  = (float*)(ws + WS_ALBUF);
    uint4*    arc    = (uint4*)(ws + WS_ARC);

    k_init   <<<512, 256, 0, stream>>>(log_init, albuf, counts, cursor, arc, flags, out);
    k_count  <<<NE/256, 256, 0, stream>>>(to_st, counts);
    k_widths <<<1, 64, 0, stream>>>(counts, widths, gbase);
    k_scatter<<<NE/256, 256, 0, stream>>>(from_st, to_st, pdf_ids, log_w, log_init,
                                          gbase, cursor, arc);
    k_fwd    <<<NSP*NBG, 1024, 0, stream>>>(x, log_final, arc, widths, gbase,
                                            albuf, flags, out);
}

// Round 10
// 2009.937 us; speedup vs baseline: 2.3670x; 2.3670x over previous
//
#include <hip/hip_runtime.h>
#include <cstdint>

#define NS 2048      // states S
#define NE 65536     // arcs E
#define ND 2048      // pdfs D
#define NB 32        // batch
#define NT 500       // frames
#define NGROUPS 32   // 64-state dest groups
#define ELLCAP (2*NE)   // uint4 entries; padded total ~102K < 131072
#define LEAKYF 0.1f
#define NBG 16       // batch groups (2 batches each)
#define NSP 16       // state partitions (128 states each)

// ws byte offsets
#define WS_COUNTS 0
#define WS_CURSOR 8192
#define WS_WIDTHS 16384
#define WS_GBASE  16640
#define WS_ALBUF  20480      // 2 par x 16 bg x 2048 x 8B = 512 KB
#define WS_ARC    544768     // ELLCAP * 16B = 2 MB

typedef float __attribute__((ext_vector_type(2))) f2v;

// ---- agent-scope (L3 coherence point) ops, proven semantics from R3-R8 ----
__device__ __forceinline__ void ld2_l3(const float2* p0, const float2* p1,
                                       float2& r0, float2& r1) {
    f2v a, b;
    asm volatile("global_load_dwordx2 %0, %2, off sc0 sc1\n\t"
                 "global_load_dwordx2 %1, %3, off sc0 sc1\n\t"
                 "s_waitcnt vmcnt(0)"
                 : "=&v"(a), "=&v"(b) : "v"(p0), "v"(p1) : "memory");
    r0 = make_float2(a.x, a.y); r1 = make_float2(b.x, b.y);
}
__device__ __forceinline__ void st2_l3(float2* p, float2 v) {
    f2v d; d.x = v.x; d.y = v.y;
    asm volatile("global_store_dwordx2 %0, %1, off sc0 sc1"
                 :: "v"(p), "v"(d) : "memory");
}

__global__ void k_init(const float* __restrict__ log_init, float* albuf, float* out,
                       uint32_t* counts, uint32_t* cursor, uint4* arcp) {
    int tid = blockIdx.x * blockDim.x + threadIdx.x;
    int n = blockDim.x * gridDim.x;
    for (int i = tid; i < NS; i += n) { counts[i] = 0u; cursor[i] = 0u; }
    for (int i = tid; i < ELLCAP; i += n) arcp[i] = make_uint4(0u, 0u, 0u, 0u);
    float2* ab = reinterpret_cast<float2*>(albuf);
    for (int i = tid; i < NBG * NS; i += n) {
        int s = i & (NS - 1);
        float a = __expf(log_init[s]);
        ab[i]            = make_float2(a, a);        // parity0 = epoch 0, sign +
        ab[NBG * NS + i] = make_float2(-1.f, -1.f);  // parity1 sentinel: stale (epoch1 expects +)
    }
    if (tid == 0) out[0] = 0.0f;
}

__global__ void k_count(const int* __restrict__ to_state, uint32_t* counts) {
    int e = blockIdx.x * blockDim.x + threadIdx.x;
    if (e < NE) atomicAdd(&counts[to_state[e]], 1u);
}

__global__ void k_widths(const uint32_t* __restrict__ counts, uint32_t* widths, uint32_t* gbase) {
    int g = threadIdx.x;
    if (g < NGROUPS) {
        uint32_t w = 0u;
        for (int i = 0; i < 64; ++i) w = max(w, counts[g*64 + i]);
        widths[g] = w;
    }
    __syncthreads();
    if (threadIdx.x == 0) {
        uint32_t acc = 0u;
        for (int g2 = 0; g2 < NGROUPS; ++g2) { gbase[g2] = acc; acc += widths[g2] * 64u; }
        gbase[NGROUPS] = acc;
    }
}

__global__ void k_scatter(const int* __restrict__ from_state, const int* __restrict__ to_state,
                          const int* __restrict__ pdf_ids, const float* __restrict__ log_w,
                          const float* __restrict__ log_init,
                          const uint32_t* __restrict__ gbase, uint32_t* cursor, uint4* arcp) {
    int e = blockIdx.x * blockDim.x + threadIdx.x;
    if (e >= NE) return;
    int s = to_state[e];
    int g = s >> 6;
    uint32_t slot = atomicAdd(&cursor[s], 1u);
    uint32_t pos = gbase[g] + slot * 64u + (uint32_t)(s & 63);
    int fs = from_state[e];
    uint32_t meta = (uint32_t)fs | ((uint32_t)pdf_ids[e] << 16);
    float w  = __expf(log_w[e]);
    float w2 = LEAKYF * __expf(log_init[fs]) * w;   // leaky-path weight
    arcp[pos] = make_uint4(meta, __float_as_uint(w), __float_as_uint(w2), 0u);
}

// 256 persistent WGs: bid = sp*16 + bg -> bid%8 = bg%8 (XCD-locked batch groups).
// Sign-epoch protocol: epoch e stored with sign (e>>1)&1 into buffer e&1.
// No flags/atomics/drains: consumers spin-load their own elements until the
// sign matches the expected epoch; producers fire-and-forget signed stores.
__global__ __launch_bounds__(1024, 1) void k_fwd(
    const float* __restrict__ x, const float* __restrict__ log_final,
    const uint4* __restrict__ arc, const uint32_t* __restrict__ widths,
    const uint32_t* __restrict__ gbase,
    float* albuf, float* out)
{
    __shared__ __align__(16) float2 e2[NS];        // 16 KB raw alpha
    __shared__ __align__(16) float2 Xs[2 * ND];    // 32 KB exp(x) double-buffered
    __shared__ __align__(16) float2 pt[16 * 64];   // 8 KB partials
    __shared__ __align__(16) float2 red[16];

    const int tid  = threadIdx.x;
    const int bg   = blockIdx.x & 15;
    const int sp   = blockIdx.x >> 4;
    const int lane = tid & 63;
    const int wid  = tid >> 6;
    const int gsel = wid >> 3;              // which of my 2 dest groups
    const int wsl  = wid & 7;               // slot-slice (8 waves/group)
    const int g    = sp * 2 + gsel;

    const float* x0 = x + (size_t)(bg * 2)     * NT * ND;
    const float* x1 = x + (size_t)(bg * 2 + 1) * NT * ND;

    // Xs[0] prologue (ordered before t=0 arc pass by (B2))
    Xs[tid]        = make_float2(__expf(x0[tid]),        __expf(x1[tid]));
    Xs[tid + 1024] = make_float2(__expf(x0[tid + 1024]), __expf(x1[tid + 1024]));

    const int wd = (int)widths[g];
    const uint4* ap = arc + gbase[g] + lane;     // slot i at ap[i*64]
    float2* albuf2 = reinterpret_cast<float2*>(albuf);

    float C0 = 0.f, C1 = 0.f;

    for (int t = 0; t < NT; ++t) {
        const int par = t & 1;
        const float2* cbuf = albuf2 + ((size_t)par * NBG + bg) * NS;
        float2*       nbuf = albuf2 + ((size_t)(par ^ 1) * NBG + bg) * NS;
        float2* Xcur = Xs + (size_t)par * ND;
        float2* Xnxt = Xs + (size_t)(par ^ 1) * ND;
        const uint32_t sexp = (uint32_t)((t >> 1) & 1);   // expected sign bit

        // spin-load alpha_t: each thread owns states {tid, tid+1024}
        float2 A0, A1;
        for (;;) {
            ld2_l3(cbuf + tid, cbuf + tid + 1024, A0, A1);
            uint32_t m = ((__float_as_uint(A0.x) >> 31) ^ sexp)
                       | ((__float_as_uint(A0.y) >> 31) ^ sexp)
                       | ((__float_as_uint(A1.x) >> 31) ^ sexp)
                       | ((__float_as_uint(A1.y) >> 31) ^ sexp);
            if (m == 0u) break;
            __builtin_amdgcn_s_sleep(1);
        }
        A0.x = fabsf(A0.x); A0.y = fabsf(A0.y);
        A1.x = fabsf(A1.x); A1.y = fabsf(A1.y);

        // x(t+1) prefetch (plain cached loads; consumed after arc pass)
        float pa0, pa1, pb0, pb1;
        const bool pf = (t + 1 < NT);
        if (pf) {
            const size_t o = (size_t)(t + 1) * ND;
            pa0 = x0[o + tid];        pb0 = x1[o + tid];
            pa1 = x0[o + tid + 1024]; pb1 = x1[o + tid + 1024];
        }

        e2[tid]        = A0;
        e2[tid + 1024] = A1;
        float u0 = A0.x + A1.x, u1 = A0.y + A1.y;
        #pragma unroll
        for (int off = 32; off > 0; off >>= 1) {
            u0 += __shfl_down(u0, off, 64);
            u1 += __shfl_down(u1, off, 64);
        }
        if (lane == 0) red[wid] = make_float2(u0, u1);
        __syncthreads();   // (B2): e2 + red + Xs[par] ready

        // every thread computes T -> invT folded into arc pass
        float T0 = 0.f, T1 = 0.f;
        #pragma unroll
        for (int j = 0; j < 16; ++j) { float2 q = red[j]; T0 += q.x; T1 += q.y; }
        const float i0 = 1.0f / T0, i1 = 1.0f / T1;
        if (tid == 0) { C0 += __logf(T0); C1 += __logf(T1); }

        // arc pass: out = sum X[pdf] * (a[src]*invT*w + w2)
        float2 acc = make_float2(0.f, 0.f);
        for (int i = wsl; i < wd; i += 8) {
            uint4 A = ap[(size_t)i * 64];
            const float w  = __uint_as_float(A.y);
            const float w2 = __uint_as_float(A.z);
            const int src = (int)(A.x & 0xFFFFu);
            const int pdf = (int)(A.x >> 16);
            float2 ev = e2[src];
            float2 xv = Xcur[pdf];
            acc.x = fmaf(xv.x, fmaf(ev.x * i0, w, w2), acc.x);
            acc.y = fmaf(xv.y, fmaf(ev.y * i1, w, w2), acc.y);
        }
        pt[wid * 64 + lane] = acc;
        if (pf) {
            Xnxt[tid]        = make_float2(__expf(pa0), __expf(pb0));
            Xnxt[tid + 1024] = make_float2(__expf(pa1), __expf(pb1));
        }
        __syncthreads();   // (C): pt ready

        // tail: waves 0 and 8 each reduce 8 partials for their 64 states and
        // fire-and-forget signed stores (no drain, no flag).
        if (wsl == 0) {
            float2 r = pt[(gsel * 8) * 64 + lane];
            #pragma unroll
            for (int k = 1; k < 8; ++k) {
                float2 q = pt[(gsel * 8 + k) * 64 + lane];
                r.x += q.x; r.y += q.y;
            }
            const float sg = (((t + 1) >> 1) & 1) ? -1.f : 1.f;
            st2_l3(nbuf + sp * 128 + gsel * 64 + lane,
                   make_float2(r.x * sg, r.y * sg));
        }
    }

    // epilogue: sp==0 WG per batch-group; epoch NT=500 lives in parity 0, sign +
    if (sp == 0) {
        const float2* fbuf = albuf2 + (size_t)bg * NS;
        const uint32_t sexp = (uint32_t)((NT >> 1) & 1);
        float2 A0, A1;
        for (;;) {
            ld2_l3(fbuf + tid, fbuf + tid + 1024, A0, A1);
            uint32_t m = ((__float_as_uint(A0.x) >> 31) ^ sexp)
                       | ((__float_as_uint(A0.y) >> 31) ^ sexp)
                       | ((__float_as_uint(A1.x) >> 31) ^ sexp)
                       | ((__float_as_uint(A1.y) >> 31) ^ sexp);
            if (m == 0u) break;
            __builtin_amdgcn_s_sleep(1);
        }
        A0.x = fabsf(A0.x); A0.y = fabsf(A0.y);
        A1.x = fabsf(A1.x); A1.y = fabsf(A1.y);
        float f0 = __expf(log_final[tid]);
        float f1 = __expf(log_final[tid + 1024]);
        float u0 = A0.x * f0 + A1.x * f1;
        float u1 = A0.y * f0 + A1.y * f1;
        #pragma unroll
        for (int off = 32; off > 0; off >>= 1) {
            u0 += __shfl_down(u0, off, 64);
            u1 += __shfl_down(u1, off, 64);
        }
        if (lane == 0) red[wid] = make_float2(u0, u1);
        __syncthreads();
        if (tid == 0) {
            float t0 = 0.f, t1 = 0.f;
            #pragma unroll
            for (int j = 0; j < 16; ++j) { t0 += red[j].x; t1 += red[j].y; }
            atomicAdd(out, -(__logf(t0) + C0) - (__logf(t1) + C1));
        }
    }
}

extern "C" void kernel_launch(void* const* d_in, const int* in_sizes, int n_in,
                              void* d_out, int out_size, void* d_ws, size_t ws_size,
                              hipStream_t stream) {
    const float* x         = (const float*)d_in[0];
    const float* log_w     = (const float*)d_in[1];
    const float* log_init  = (const float*)d_in[2];
    const float* log_final = (const float*)d_in[3];
    const int*   from_st   = (const int*)d_in[4];
    const int*   to_st     = (const int*)d_in[5];
    const int*   pdf_ids   = (const int*)d_in[6];
    float* out = (float*)d_out;

    uint8_t* ws = (uint8_t*)d_ws;
    uint32_t* counts = (uint32_t*)(ws + WS_COUNTS);
    uint32_t* cursor = (uint32_t*)(ws + WS_CURSOR);
    uint32_t* widths = (uint32_t*)(ws + WS_WIDTHS);
    uint32_t* gbase  = (uint32_t*)(ws + WS_GBASE);
    float*    albuf  = (float*)(ws + WS_ALBUF);
    uint4*    arc    = (uint4*)(ws + WS_ARC);

    k_init   <<<512, 256, 0, stream>>>(log_init, albuf, out, counts, cursor, arc);
    k_count  <<<NE/256, 256, 0, stream>>>(to_st, counts);
    k_widths <<<1, 64, 0, stream>>>(counts, widths, gbase);
    k_scatter<<<NE/256, 256, 0, stream>>>(from_st, to_st, pdf_ids, log_w, log_init,
                                          gbase, cursor, arc);
    k_fwd    <<<NSP*NBG, 1024, 0, stream>>>(x, log_final, arc, widths, gbase,
                                            albuf, out);
}